// Round 9
// baseline (199.858 us; speedup 1.0000x reference)
//
#include <hip/hip_runtime.h>
#include <hip/hip_bf16.h>
#include <math.h>

// Problem constants (B=2, C=128, G=16, Cg=8, K=3, H=W=192)
#define BB 2
#define CC 128
#define GG 16
#define CG 8
#define HH 192
#define WW 192
#define HM 190
#define WM 190
#define LL (HM * WM)          // 36100
#define HWSZ (HH * WW)        // 36864
#define NTRIPLE (BB * GG * 9) // 288
#define SPLIT 6               // row slices for phase1 parallelism
#define ROWS_PER_SLICE 32     // 6*32 >= 190

typedef float float4a __attribute__((ext_vector_type(4), aligned(4)));
typedef float float4v __attribute__((ext_vector_type(4)));
typedef float float2v __attribute__((ext_vector_type(2), aligned(8)));

// Module-owned scratch (d_ws size unverified; writing it corrupted the
// harness pristine input copy in R0). Everything below is fully rewritten
// on every call before being read (same stream) -> identical work per call.
__device__ float g_part[NTRIPLE * SPLIT * 36]; // per-slice partial sums
__device__ int g_rel[BB * GG * 72];            // phase2: neighbor rel offset
__device__ float g_scl[BB * GG * 72];          // phase2: c_max/8

// -------- Phase 1a: aligned-window, high-ILP Gram partials ----------------
// R8 evidence: VALU-busy ~= instruction floor; the other ~58% of the wall is
// exposed load latency (VGPR=52 schedule -> no cross-iter prefetch, small
// load batches possibly scalarized by align-4 vectors). v3: per iteration a
// thread handles 8 consecutive px with a 10-float 16B/8B-ALIGNED window per
// (channel,ki) row (b128+b128+b64, never split), 9-18 independent loads
// up-front, then 288 FMAs -- ~2x work per latency window, guaranteed vector
// loads. Body specialized on j so all indices are compile-time constants.
template <int J>
__device__ __forceinline__ void gram_slice(const float* __restrict__ pA,
                                           const float* __restrict__ pB,
                                           int y0, int rows, int tid,
                                           float acc[36]) {
  constexpr int CA = (8 * J) / 9;
  constexpr int CB = (8 * J + 7) / 9;
  constexpr int NCH = (CB > CA) ? 2 : 1;

  // ---- main: pairs of 4-px groups, x0 in {0,8,...,176}, px [0,184) ----
  const int npair = rows * 23;
  for (int q = tid; q < npair; q += 256) {
    const int y = y0 + q / 23;
    const int x0 = (q % 23) * 8;
    const int ro = y * WW + x0;

    float w[NCH][3][10];
#pragma unroll
    for (int ci = 0; ci < NCH; ++ci) {
      const float* pc = ci ? pB : pA;
#pragma unroll
      for (int ki = 0; ki < 3; ++ki) {
        const float4v a = *(const float4v*)(pc + ro + ki * WW);
        const float4v bq = *(const float4v*)(pc + ro + ki * WW + 4);
        const float2v cq = *(const float2v*)(pc + ro + ki * WW + 8);
        w[ci][ki][0] = a.x; w[ci][ki][1] = a.y;
        w[ci][ki][2] = a.z; w[ci][ki][3] = a.w;
        w[ci][ki][4] = bq.x; w[ci][ki][5] = bq.y;
        w[ci][ki][6] = bq.z; w[ci][ki][7] = bq.w;
        w[ci][ki][8] = cq.x; w[ci][ki][9] = cq.y;
      }
    }
    // squares
#pragma unroll
    for (int d = 0; d < 8; ++d) {
      const int f = 8 * J + d;
      const int ci = f / 9 - CA;
      const int k = f % 9;
      const int ki = k / 3, kj = k % 3;
      float s = 0.0f;
#pragma unroll
      for (int e = 0; e < 8; ++e) s += w[ci][ki][kj + e] * w[ci][ki][kj + e];
      acc[d] += s;
    }
    // cross products (same (c,d) order phase1b expects)
    int p = 8;
#pragma unroll
    for (int c = 0; c < 8; ++c) {
      const int f1 = 8 * J + c;
      const int ci1 = f1 / 9 - CA;
      const int k1 = f1 % 9;
      const int ki1 = k1 / 3, kj1 = k1 % 3;
#pragma unroll
      for (int d = c + 1; d < 8; ++d) {
        const int f2 = 8 * J + d;
        const int ci2 = f2 / 9 - CA;
        const int k2 = f2 % 9;
        const int ki2 = k2 / 3, kj2 = k2 % 3;
        float s = 0.0f;
#pragma unroll
        for (int e = 0; e < 8; ++e)
          s += w[ci1][ki1][kj1 + e] * w[ci2][ki2][kj2 + e];
        acc[p++] += s;
      }
    }
  }

  // ---- cleanup: px x in [184,190), scalar ----
  const int ncl = rows * 6;
  for (int t = tid; t < ncl; t += 256) {
    const int y = y0 + t / 6;
    const int x = 184 + t % 6;
    float v[8];
#pragma unroll
    for (int d = 0; d < 8; ++d) {
      const int f = 8 * J + d;
      const int ci = f / 9 - CA;
      const int k = f % 9;
      const int ki = k / 3, kj = k % 3;
      v[d] = (ci ? pB : pA)[(y + ki) * WW + x + kj];
    }
#pragma unroll
    for (int d = 0; d < 8; ++d) acc[d] += v[d] * v[d];
    int p = 8;
#pragma unroll
    for (int c = 0; c < 8; ++c)
#pragma unroll
      for (int d = c + 1; d < 8; ++d) acc[p++] += v[c] * v[d];
  }
}

__global__ __launch_bounds__(256, 4) void phase1a_kernel(
    const float* __restrict__ feat) {
  const int B = blockIdx.x;      // 0..1727
  const int xcd = B & 7;         // XCD-locality swizzle (kept: halved FETCH)
  const int slot = B >> 3;       // 0..215
  const int unit = xcd * 4 + slot / 54; // (b,g) composite, 0..31
  const int r = slot % 54;
  const int j = r / 6;
  const int sl = r % 6;
  const int b = unit >> 4;
  const int g = unit & 15;

  const int cA = (8 * j) / 9;
  const int cB = (8 * j + 7) / 9;
  const float* pA = feat + (size_t)(b * CC + g * CG + cA) * HWSZ;
  const float* pB = feat + (size_t)(b * CC + g * CG + cB) * HWSZ;

  const int y0 = sl * ROWS_PER_SLICE;
  const int y1 = (y0 + ROWS_PER_SLICE < HM) ? y0 + ROWS_PER_SLICE : HM;
  const int rows = y1 - y0;
  const int tid = (int)threadIdx.x;

  float acc[36];
#pragma unroll
  for (int i = 0; i < 36; ++i) acc[i] = 0.0f;

  switch (j) {
    case 0: gram_slice<0>(pA, pB, y0, rows, tid, acc); break;
    case 1: gram_slice<1>(pA, pB, y0, rows, tid, acc); break;
    case 2: gram_slice<2>(pA, pB, y0, rows, tid, acc); break;
    case 3: gram_slice<3>(pA, pB, y0, rows, tid, acc); break;
    case 4: gram_slice<4>(pA, pB, y0, rows, tid, acc); break;
    case 5: gram_slice<5>(pA, pB, y0, rows, tid, acc); break;
    case 6: gram_slice<6>(pA, pB, y0, rows, tid, acc); break;
    case 7: gram_slice<7>(pA, pB, y0, rows, tid, acc); break;
    default: gram_slice<8>(pA, pB, y0, rows, tid, acc); break;
  }

  // Wave shuffle reduce (64 lanes) then LDS across 4 waves.
  __shared__ float red[36 * 4];
  const int lane = tid & 63;
  const int wave = tid >> 6;
#pragma unroll
  for (int i = 0; i < 36; ++i) {
    float v = acc[i];
    for (int o = 32; o > 0; o >>= 1) v += __shfl_down(v, o, 64);
    if (lane == 0) red[i * 4 + wave] = v;
  }
  __syncthreads();
  if (tid < 36) {
    const int i = tid;
    const int tri = unit * 9 + j;
    g_part[(tri * SPLIT + sl) * 36 + i] =
        red[i * 4] + red[i * 4 + 1] + red[i * 4 + 2] + red[i * 4 + 3];
  }
}

// -------- Phase 1b: reduce slices, 8x8 argmin, emit phase2 tables ---------
__global__ __launch_bounds__(64) void phase1b_kernel() {
  const int tri = blockIdx.x * 64 + (int)threadIdx.x;
  if (tri >= NTRIPLE) return;
  const int b = tri / (GG * 9);
  const int rem = tri % (GG * 9);
  const int g = rem / 9;
  const int j = rem % 9;

  float tot[36];
#pragma unroll
  for (int i = 0; i < 36; ++i) tot[i] = 0.0f;
  for (int s = 0; s < SPLIT; ++s)
#pragma unroll
    for (int i = 0; i < 36; ++i) tot[i] += g_part[(tri * SPLIT + s) * 36 + i];

  float sq[8], gm[8][8];
#pragma unroll
  for (int i = 0; i < 8; ++i) sq[i] = tot[i];
  {
    int p = 8;
    for (int c = 0; c < 8; ++c)
      for (int d = c + 1; d < 8; ++d) {
        gm[c][d] = tot[p];
        gm[d][c] = tot[p];
        ++p;
      }
  }
  // per-row argmin with inf diagonal, first-occurrence tie-break
  int nn[8];
  for (int c = 0; c < 8; ++c) {
    float best = INFINITY;
    int bi = 0;
    for (int d = 0; d < 8; ++d) {
      if (d == c) continue;
      const float d2 = sq[c] + sq[d] - 2.0f * gm[c][d];
      if (d2 < best) {
        best = d2;
        bi = d;
      }
    }
    nn[c] = bi;
  }
  int um = 0;
  for (int c = 0; c < 8; ++c) um = um > nn[c] ? um : nn[c];
  int cnt = 0;
  for (int c = 0; c < 8; ++c) cnt += (nn[c] == um) ? 1 : 0;

  // scale = c_max/8 (exact: int * power of two); rel = neighbor offset
  // relative to the query pixel, constant over (h,w).
  const float sc = (float)cnt * 0.125f;
  const int fn = j * 8 + um;
  const int cn = fn / 9;
  const int kn = fn % 9;
  const int kin = kn / 3, kjn = kn % 3;
  for (int d = 0; d < 8; ++d) {
    const int f = j * 8 + d;
    const int cl = f / 9;
    const int k = f % 9;
    const int ki = k / 3, kj = k % 3;
    const int rel = (cn - cl) * HWSZ + (kin - ki) * WW + (kjn - kj);
    const int tix = (b * GG + g) * 72 + f;
    g_rel[tix] = rel;
    g_scl[tix] = sc;
  }
}

// -------- Phase 2 main: interior float4 groups, no masks ------------------
// XCD-locality swizzle: all 144 blocks (8 planes x 18) of one (b,g) unit on
// one XCD. 2 float4 groups per thread amortize the table prologue.
// Edge pixels are skipped here and written by phase2_edge (disjoint sets).
__global__ __launch_bounds__(256) void phase2_main_kernel(
    const float* __restrict__ feat, float* __restrict__ out) {
  const int B = blockIdx.x;      // 0..4607
  const int xcd = B & 7;
  const int slot = B >> 3;       // 0..575
  const int unit = xcd * 4 + slot / 144; // (b,g) composite, 0..31
  const int r = slot % 144;
  const int cl = r / 18;         // local channel 0..7
  const int blk = r % 18;        // 18 x 2048 px = one plane
  const int plane = unit * 8 + cl; // == b*CC + ch

  const int tbase = unit * 72 + cl * 9;
  int rel[9];
  float scl[9];
#pragma unroll
  for (int k = 0; k < 9; ++k) {
    rel[k] = g_rel[tbase + k];
    scl[k] = g_scl[tbase + k];
  }

  const float* pb = feat + (size_t)plane * HWSZ;
  float* ob = out + (size_t)plane * HWSZ;
  const bool b1 = (unit >= GG); // b != 0
  const int i0 = blk * 2048 + (int)threadIdx.x * 4;

#pragma unroll
  for (int gidx = 0; gidx < 2; ++gidx) {
    const int inner = i0 + gidx * 1024;
    const int h = inner / WW;
    const int w0 = inner % WW;
    if (h >= 2 && h < HM && w0 >= 4 && w0 < 188) {
      const float* p = pb + inner;
      const float4v v = *(const float4v*)p;
      float4v acc = {0.0f, 0.0f, 0.0f, 0.0f};
#pragma unroll
      for (int k = 0; k < 9; ++k) {
        const float4a n = *(const float4a*)(p + rel[k]);
        const float s = scl[k];
        // exact reference op order: round(v*n*cm)/8 == round(v*n*(cm/8))
        acc.x += floorf(v.x * n.x * s);
        acc.y += floorf(v.y * n.y * s);
        acc.z += floorf(v.z * n.z * s);
        acc.w += floorf(v.w * n.w * s);
      }
      if (b1) { // interior => n_valid = 9
        acc.x += 9.0f * v.x;
        acc.y += 9.0f * v.y;
        acc.z += 9.0f * v.z;
        acc.w += 9.0f * v.w;
      }
      *(float4v*)(ob + inner) = acc;
    }
  }
}

// -------- Phase 2 edge: border pixels, clamped scalar path ----------------
// 2272 px per plane: rows {0,1,190,191} (768) + cols {0..3,188..191} for
// h in [2,190) (1504). 256 planes * 2272 = 581632 = 2272 blocks * 256.
__global__ __launch_bounds__(256) void phase2_edge_kernel(
    const float* __restrict__ feat, float* __restrict__ out) {
  const int gid = blockIdx.x * 256 + (int)threadIdx.x;
  const int plane = gid / 2272;
  const int ei = gid % 2272;
  int h, w;
  if (ei < 768) {
    const int r = ei / WW; // 0..3
    h = (r < 2) ? r : r + 188; // 0,1,190,191
    w = ei % WW;
  } else {
    const int e2 = ei - 768;
    h = 2 + (e2 >> 3);
    const int w8 = e2 & 7;
    w = (w8 < 4) ? w8 : w8 + 184; // 0..3, 188..191
  }
  const int g = (plane % CC) >> 3;
  const int cl = (plane % CC) & 7;
  const int tbase = ((plane / CC) * GG + g) * 72 + cl * 9;

  int rel[9];
  float scl[9];
#pragma unroll
  for (int k = 0; k < 9; ++k) {
    rel[k] = g_rel[tbase + k];
    scl[k] = g_scl[tbase + k];
  }

  const int idx = plane * HWSZ + h * WW + w;
  const float* p = feat + idx;
  const float v = *p;
  float acc = 0.0f;
  int nv = 0;
#pragma unroll
  for (int k = 0; k < 9; ++k) {
    const int ki = k / 3, kj = k % 3; // compile-time
    const int y = h - ki, x = w - kj;
    const bool valid = ((unsigned)y < (unsigned)HM) & ((unsigned)x < (unsigned)WM);
    const int o = valid ? rel[k] : 0; // clamp keeps the load in-bounds
    const float n = p[o];
    const float fl = floorf(v * n * scl[k]);
    acc += valid ? fl : 0.0f;
    nv += valid ? 1 : 0;
  }
  if (plane >= CC) acc += (float)nv * v;
  out[idx] = acc;
}

extern "C" void kernel_launch(void* const* d_in, const int* in_sizes, int n_in,
                              void* d_out, int out_size, void* d_ws,
                              size_t ws_size, hipStream_t stream) {
  const float* feat = (const float*)d_in[0];
  float* out = (float*)d_out;
  (void)d_ws;
  (void)ws_size;

  phase1a_kernel<<<NTRIPLE * SPLIT, 256, 0, stream>>>(feat);
  phase1b_kernel<<<(NTRIPLE + 63) / 64, 64, 0, stream>>>();

  phase2_main_kernel<<<BB * CC * 18, 256, 0, stream>>>(feat, out);
  phase2_edge_kernel<<<2272, 256, 0, stream>>>(feat, out);
}

// Round 10
// 132.003 us; speedup vs baseline: 1.5140x; 1.5140x over previous
//
#include <hip/hip_runtime.h>
#include <hip/hip_bf16.h>
#include <math.h>

// Problem constants (B=2, C=128, G=16, Cg=8, K=3, H=W=192)
#define BB 2
#define CC 128
#define GG 16
#define CG 8
#define HH 192
#define WW 192
#define HM 190
#define WM 190
#define LL (HM * WM)          // 36100
#define HWSZ (HH * WW)        // 36864
#define NTRIPLE (BB * GG * 9) // 288
#define SPLIT 6               // row slices for phase1 parallelism
#define ROWS_PER_SLICE 32     // 6*32 >= 190

typedef float float4a __attribute__((ext_vector_type(4), aligned(4)));
typedef float float4v __attribute__((ext_vector_type(4)));

// Module-owned scratch (d_ws size unverified; writing it corrupted the
// harness pristine input copy in R0). Everything below is fully rewritten
// on every call before being read (same stream) -> identical work per call.
__device__ float g_part[NTRIPLE * SPLIT * 36]; // per-slice partial sums
__device__ int g_rel[BB * GG * 72];            // phase2: neighbor rel offset
__device__ float g_scl[BB * GG * 72];          // phase2: c_max/8

// Is LDS/global row (ci,ki) referenced by any of triple J's 8 vectors?
constexpr bool row_used(int J, int ci, int ki) {
  for (int d = 0; d < 8; ++d) {
    const int f = 8 * J + d;
    if ((f / 9 - (8 * J) / 9) == ci && (f % 9) / 3 == ki) return true;
  }
  return false;
}

// -------- Phase 1a: aligned-window, high-ILP Gram partials (v4) -----------
// R9 post-mortem: the windowed body SPILLED (W RITE_SIZE 155 MB of scratch,
// VGPR stuck at 64). v4: 128-thread blocks + __launch_bounds__(128,2)
// raise the per-wave VGPR cap to 256, and the window shrinks to
// w[ch][3][8] (2 naturally-aligned float4 loads per used row; never
// split). Per 4-px group: 6-12 vector loads -> 144 FMAs. Pixels
// x in {188,189} handled by a scalar cleanup loop.
template <int J>
__device__ __forceinline__ void gram_slice(const float* __restrict__ pA,
                                           const float* __restrict__ pB,
                                           int y0, int rows, int tid,
                                           float acc[36]) {
  constexpr int CA = (8 * J) / 9;
  constexpr int CB = (8 * J + 7) / 9;
  constexpr int NCH = (CB > CA) ? 2 : 1;

  // ---- main: 4-px groups, x0 in {0,4,...,184}, px x in [0,188) ----
  const int ngrp = rows * 47;
  for (int q = tid; q < ngrp; q += 128) {
    const int y = y0 + q / 47;
    const int x0 = (q % 47) * 4;
    const int ro = y * WW + x0; // multiple of 4 -> 16B-aligned address

    float w[NCH][3][8];
#pragma unroll
    for (int ci = 0; ci < NCH; ++ci) {
      const float* pc = ci ? pB : pA;
#pragma unroll
      for (int ki = 0; ki < 3; ++ki) {
        if (row_used(J, ci, ki)) {
          const float4v a = *(const float4v*)(pc + ro + ki * WW);
          const float4v bq = *(const float4v*)(pc + ro + ki * WW + 4);
          w[ci][ki][0] = a.x; w[ci][ki][1] = a.y;
          w[ci][ki][2] = a.z; w[ci][ki][3] = a.w;
          w[ci][ki][4] = bq.x; w[ci][ki][5] = bq.y;
          w[ci][ki][6] = bq.z; w[ci][ki][7] = bq.w;
        }
      }
    }
    // squares
#pragma unroll
    for (int d = 0; d < 8; ++d) {
      constexpr_helper_sq:;
      const int f = 8 * J + d;
      const int ci = f / 9 - CA;
      const int k = f % 9;
      const int ki = k / 3, kj = k % 3;
      float s = 0.0f;
#pragma unroll
      for (int e = 0; e < 4; ++e) s += w[ci][ki][kj + e] * w[ci][ki][kj + e];
      acc[d] += s;
    }
    // cross products (same (c,d) order phase1b expects)
    int p = 8;
#pragma unroll
    for (int c = 0; c < 8; ++c) {
      const int f1 = 8 * J + c;
      const int ci1 = f1 / 9 - CA;
      const int k1 = f1 % 9;
      const int ki1 = k1 / 3, kj1 = k1 % 3;
#pragma unroll
      for (int d = c + 1; d < 8; ++d) {
        const int f2 = 8 * J + d;
        const int ci2 = f2 / 9 - CA;
        const int k2 = f2 % 9;
        const int ki2 = k2 / 3, kj2 = k2 % 3;
        float s = 0.0f;
#pragma unroll
        for (int e = 0; e < 4; ++e)
          s += w[ci1][ki1][kj1 + e] * w[ci2][ki2][kj2 + e];
        acc[p++] += s;
      }
    }
  }

  // ---- cleanup: px x in {188,189}, scalar ----
  const int ncl = rows * 2;
  for (int t = tid; t < ncl; t += 128) {
    const int y = y0 + t / 2;
    const int x = 188 + (t & 1);
    float v[8];
#pragma unroll
    for (int d = 0; d < 8; ++d) {
      const int f = 8 * J + d;
      const int ci = f / 9 - CA;
      const int k = f % 9;
      const int ki = k / 3, kj = k % 3;
      v[d] = (ci ? pB : pA)[(y + ki) * WW + x + kj];
    }
#pragma unroll
    for (int d = 0; d < 8; ++d) acc[d] += v[d] * v[d];
    int p = 8;
#pragma unroll
    for (int c = 0; c < 8; ++c)
#pragma unroll
      for (int d = c + 1; d < 8; ++d) acc[p++] += v[c] * v[d];
  }
}

__global__ __launch_bounds__(128, 2) void phase1a_kernel(
    const float* __restrict__ feat) {
  const int B = blockIdx.x;      // 0..1727
  const int xcd = B & 7;         // XCD-locality swizzle (kept: halved FETCH)
  const int slot = B >> 3;       // 0..215
  const int unit = xcd * 4 + slot / 54; // (b,g) composite, 0..31
  const int r = slot % 54;
  const int j = r / 6;
  const int sl = r % 6;
  const int b = unit >> 4;
  const int g = unit & 15;

  const int cA = (8 * j) / 9;
  const int cB = (8 * j + 7) / 9;
  const float* pA = feat + (size_t)(b * CC + g * CG + cA) * HWSZ;
  const float* pB = feat + (size_t)(b * CC + g * CG + cB) * HWSZ;

  const int y0 = sl * ROWS_PER_SLICE;
  const int y1 = (y0 + ROWS_PER_SLICE < HM) ? y0 + ROWS_PER_SLICE : HM;
  const int rows = y1 - y0;
  const int tid = (int)threadIdx.x;

  float acc[36];
#pragma unroll
  for (int i = 0; i < 36; ++i) acc[i] = 0.0f;

  switch (j) {
    case 0: gram_slice<0>(pA, pB, y0, rows, tid, acc); break;
    case 1: gram_slice<1>(pA, pB, y0, rows, tid, acc); break;
    case 2: gram_slice<2>(pA, pB, y0, rows, tid, acc); break;
    case 3: gram_slice<3>(pA, pB, y0, rows, tid, acc); break;
    case 4: gram_slice<4>(pA, pB, y0, rows, tid, acc); break;
    case 5: gram_slice<5>(pA, pB, y0, rows, tid, acc); break;
    case 6: gram_slice<6>(pA, pB, y0, rows, tid, acc); break;
    case 7: gram_slice<7>(pA, pB, y0, rows, tid, acc); break;
    default: gram_slice<8>(pA, pB, y0, rows, tid, acc); break;
  }

  // Wave shuffle reduce (64 lanes) then LDS across 2 waves.
  __shared__ float red[36 * 2];
  const int lane = tid & 63;
  const int wave = tid >> 6;
#pragma unroll
  for (int i = 0; i < 36; ++i) {
    float v = acc[i];
    for (int o = 32; o > 0; o >>= 1) v += __shfl_down(v, o, 64);
    if (lane == 0) red[i * 2 + wave] = v;
  }
  __syncthreads();
  if (tid < 36) {
    const int i = tid;
    const int tri = unit * 9 + j;
    g_part[(tri * SPLIT + sl) * 36 + i] = red[i * 2] + red[i * 2 + 1];
  }
}

// -------- Phase 1b: reduce slices, 8x8 argmin, emit phase2 tables ---------
__global__ __launch_bounds__(64) void phase1b_kernel() {
  const int tri = blockIdx.x * 64 + (int)threadIdx.x;
  if (tri >= NTRIPLE) return;
  const int b = tri / (GG * 9);
  const int rem = tri % (GG * 9);
  const int g = rem / 9;
  const int j = rem % 9;

  float tot[36];
#pragma unroll
  for (int i = 0; i < 36; ++i) tot[i] = 0.0f;
  for (int s = 0; s < SPLIT; ++s)
#pragma unroll
    for (int i = 0; i < 36; ++i) tot[i] += g_part[(tri * SPLIT + s) * 36 + i];

  float sq[8], gm[8][8];
#pragma unroll
  for (int i = 0; i < 8; ++i) sq[i] = tot[i];
  {
    int p = 8;
    for (int c = 0; c < 8; ++c)
      for (int d = c + 1; d < 8; ++d) {
        gm[c][d] = tot[p];
        gm[d][c] = tot[p];
        ++p;
      }
  }
  // per-row argmin with inf diagonal, first-occurrence tie-break
  int nn[8];
  for (int c = 0; c < 8; ++c) {
    float best = INFINITY;
    int bi = 0;
    for (int d = 0; d < 8; ++d) {
      if (d == c) continue;
      const float d2 = sq[c] + sq[d] - 2.0f * gm[c][d];
      if (d2 < best) {
        best = d2;
        bi = d;
      }
    }
    nn[c] = bi;
  }
  int um = 0;
  for (int c = 0; c < 8; ++c) um = um > nn[c] ? um : nn[c];
  int cnt = 0;
  for (int c = 0; c < 8; ++c) cnt += (nn[c] == um) ? 1 : 0;

  // scale = c_max/8 (exact: int * power of two); rel = neighbor offset
  // relative to the query pixel, constant over (h,w).
  const float sc = (float)cnt * 0.125f;
  const int fn = j * 8 + um;
  const int cn = fn / 9;
  const int kn = fn % 9;
  const int kin = kn / 3, kjn = kn % 3;
  for (int d = 0; d < 8; ++d) {
    const int f = j * 8 + d;
    const int cl = f / 9;
    const int k = f % 9;
    const int ki = k / 3, kj = k % 3;
    const int rel = (cn - cl) * HWSZ + (kin - ki) * WW + (kjn - kj);
    const int tix = (b * GG + g) * 72 + f;
    g_rel[tix] = rel;
    g_scl[tix] = sc;
  }
}

// -------- Phase 2 main: interior float4 groups, no masks ------------------
// XCD-locality swizzle: all 144 blocks (8 planes x 18) of one (b,g) unit on
// one XCD. 2 float4 groups per thread amortize the table prologue.
// Edge pixels are skipped here and written by phase2_edge (disjoint sets).
__global__ __launch_bounds__(256) void phase2_main_kernel(
    const float* __restrict__ feat, float* __restrict__ out) {
  const int B = blockIdx.x;      // 0..4607
  const int xcd = B & 7;
  const int slot = B >> 3;       // 0..575
  const int unit = xcd * 4 + slot / 144; // (b,g) composite, 0..31
  const int r = slot % 144;
  const int cl = r / 18;         // local channel 0..7
  const int blk = r % 18;        // 18 x 2048 px = one plane
  const int plane = unit * 8 + cl; // == b*CC + ch

  const int tbase = unit * 72 + cl * 9;
  int rel[9];
  float scl[9];
#pragma unroll
  for (int k = 0; k < 9; ++k) {
    rel[k] = g_rel[tbase + k];
    scl[k] = g_scl[tbase + k];
  }

  const float* pb = feat + (size_t)plane * HWSZ;
  float* ob = out + (size_t)plane * HWSZ;
  const bool b1 = (unit >= GG); // b != 0
  const int i0 = blk * 2048 + (int)threadIdx.x * 4;

#pragma unroll
  for (int gidx = 0; gidx < 2; ++gidx) {
    const int inner = i0 + gidx * 1024;
    const int h = inner / WW;
    const int w0 = inner % WW;
    if (h >= 2 && h < HM && w0 >= 4 && w0 < 188) {
      const float* p = pb + inner;
      const float4v v = *(const float4v*)p;
      float4v acc = {0.0f, 0.0f, 0.0f, 0.0f};
#pragma unroll
      for (int k = 0; k < 9; ++k) {
        const float4a n = *(const float4a*)(p + rel[k]);
        const float s = scl[k];
        // exact reference op order: round(v*n*cm)/8 == round(v*n*(cm/8))
        acc.x += floorf(v.x * n.x * s);
        acc.y += floorf(v.y * n.y * s);
        acc.z += floorf(v.z * n.z * s);
        acc.w += floorf(v.w * n.w * s);
      }
      if (b1) { // interior => n_valid = 9
        acc.x += 9.0f * v.x;
        acc.y += 9.0f * v.y;
        acc.z += 9.0f * v.z;
        acc.w += 9.0f * v.w;
      }
      *(float4v*)(ob + inner) = acc;
    }
  }
}

// -------- Phase 2 edge: border pixels, clamped scalar path ----------------
// 2272 px per plane: rows {0,1,190,191} (768) + cols {0..3,188..191} for
// h in [2,190) (1504). 256 planes * 2272 = 581632 = 2272 blocks * 256.
__global__ __launch_bounds__(256) void phase2_edge_kernel(
    const float* __restrict__ feat, float* __restrict__ out) {
  const int gid = blockIdx.x * 256 + (int)threadIdx.x;
  const int plane = gid / 2272;
  const int ei = gid % 2272;
  int h, w;
  if (ei < 768) {
    const int r = ei / WW; // 0..3
    h = (r < 2) ? r : r + 188; // 0,1,190,191
    w = ei % WW;
  } else {
    const int e2 = ei - 768;
    h = 2 + (e2 >> 3);
    const int w8 = e2 & 7;
    w = (w8 < 4) ? w8 : w8 + 184; // 0..3, 188..191
  }
  const int g = (plane % CC) >> 3;
  const int cl = (plane % CC) & 7;
  const int tbase = ((plane / CC) * GG + g) * 72 + cl * 9;

  int rel[9];
  float scl[9];
#pragma unroll
  for (int k = 0; k < 9; ++k) {
    rel[k] = g_rel[tbase + k];
    scl[k] = g_scl[tbase + k];
  }

  const int idx = plane * HWSZ + h * WW + w;
  const float* p = feat + idx;
  const float v = *p;
  float acc = 0.0f;
  int nv = 0;
#pragma unroll
  for (int k = 0; k < 9; ++k) {
    const int ki = k / 3, kj = k % 3; // compile-time
    const int y = h - ki, x = w - kj;
    const bool valid = ((unsigned)y < (unsigned)HM) & ((unsigned)x < (unsigned)WM);
    const int o = valid ? rel[k] : 0; // clamp keeps the load in-bounds
    const float n = p[o];
    const float fl = floorf(v * n * scl[k]);
    acc += valid ? fl : 0.0f;
    nv += valid ? 1 : 0;
  }
  if (plane >= CC) acc += (float)nv * v;
  out[idx] = acc;
}

extern "C" void kernel_launch(void* const* d_in, const int* in_sizes, int n_in,
                              void* d_out, int out_size, void* d_ws,
                              size_t ws_size, hipStream_t stream) {
  const float* feat = (const float*)d_in[0];
  float* out = (float*)d_out;
  (void)d_ws;
  (void)ws_size;

  phase1a_kernel<<<NTRIPLE * SPLIT, 128, 0, stream>>>(feat);
  phase1b_kernel<<<(NTRIPLE + 63) / 64, 64, 0, stream>>>();

  phase2_main_kernel<<<BB * CC * 18, 256, 0, stream>>>(feat, out);
  phase2_edge_kernel<<<2272, 256, 0, stream>>>(feat, out);
}